// Round 6
// baseline (209.031 us; speedup 1.0000x reference)
//
#include <hip/hip_runtime.h>
#include <hip/hip_bf16.h>

typedef __attribute__((ext_vector_type(8))) short bf16x8;
typedef __attribute__((ext_vector_type(4))) short s16x4;
typedef __attribute__((ext_vector_type(4))) float f32x4;

#define LDKP 72   // P-buffer row stride in shorts (b128-aligned)

// packed f32x2 -> bf16x2 (RNE)
__device__ __forceinline__ unsigned pk2(float a, float b) {
    union { __hip_bfloat162 h2; unsigned u; } c;
    c.h2 = __float22bfloat162_rn(make_float2(a, b));
    return c.u;
}

// async global->LDS DMA, 16 B/lane; LDS dest = wave-uniform base + lane*16
__device__ __forceinline__ void gld16(const void* g, void* l) {
    __builtin_amdgcn_global_load_lds(
        (const __attribute__((address_space(1))) unsigned*)g,
        (__attribute__((address_space(3))) unsigned*)l, 16, 0, 0);
}

// exact transcription of the reference _hilbert_index_to_xy; returns p = x*d + y
__device__ inline int hilbert_p(int index, int d) {
    int x = 0, y = 0;
    for (int s = 1; s < d; s <<= 1) {
        int rx = (index >> 1) & 1;
        int ry = (index ^ rx) & 1;
        if (ry == 0) {
            if (rx == 1) {
                int nx = s - 1 - y;
                int ny = s - 1 - x;
                x = nx; y = ny;
            }
            int t = x; x = y; y = t;
        }
        x += s * rx;
        y += s * ry;
        index >>= 2;
    }
    return x * d + y;
}

// One block per 64-key tile (1120 tiles: g0=640, g1=320, g2=160).
// Hilbert computed once per key. Writes the exact linear byte layouts attn
// DMAs into LDS:
//   Kp tile: key-major, 16B chunks XOR-swizzled: off = j*64 + ((c8^(j&7))*8) shorts
//   Vp tile: dim-major (pre-transposed), same:   off = d*64 + ((k8^(d&7))*8) shorts
__global__ __launch_bounds__(256) void gather_kv(
    const float* __restrict__ K, const float* __restrict__ V,
    short* __restrict__ Kp, short* __restrict__ Vp)
{
    __shared__ short vt[64 * LDKP];
    __shared__ int pidx[64];

    const int b = blockIdx.x;
    int g, rb;
    if (b < 640)      { g = 0; rb = b; }
    else if (b < 960) { g = 1; rb = b - 640; }
    else              { g = 2; rb = b - 960; }
    const int nseg   = 4 >> g;
    const int hl     = rb / (nseg * 32);
    const int r2     = rb - hl * (nseg * 32);
    const int seg    = r2 >> 5;
    const int kt     = r2 & 31;
    const int h      = g * 5 + hl;
    const int S      = 2048 << g;
    const int segrow = seg * S;
    const int dgrid  = (g == 2) ? 128 : 64;
    const size_t tile_s = (size_t)b * 4096;   // tile base in shorts (8 KB/tile)

    if (threadIdx.x < 64) {
        const int j  = threadIdx.x;
        const int ii = kt * 64 + j;
        pidx[j] = (g == 0) ? ii : hilbert_p(ii << g, dgrid);
    }
    __syncthreads();

    // phase 1: gather+convert rows (key-major); K straight to global, V to LDS
    for (int it = threadIdx.x; it < 512; it += 256) {
        const int j  = it >> 3;
        const int c8 = it & 7;
        const int p  = pidx[j];
        const size_t src = ((size_t)((segrow + p) * 16 + h)) * 64 + c8 * 8;
        const float4* kp = (const float4*)(K + src);
        const float4* vp = (const float4*)(V + src);
        float4 k0 = kp[0], k1 = kp[1];
        float4 v0 = vp[0], v1 = vp[1];
        union { unsigned u[4]; bf16x8 v; } ck, cv;
        ck.u[0] = pk2(k0.x, k0.y); ck.u[1] = pk2(k0.z, k0.w);
        ck.u[2] = pk2(k1.x, k1.y); ck.u[3] = pk2(k1.z, k1.w);
        cv.u[0] = pk2(v0.x, v0.y); cv.u[1] = pk2(v0.z, v0.w);
        cv.u[2] = pk2(v1.x, v1.y); cv.u[3] = pk2(v1.z, v1.w);
        *(bf16x8*)&Kp[tile_s + j * 64 + ((c8 ^ (j & 7)) * 8)] = ck.v;
        *(bf16x8*)&vt[j * LDKP + c8 * 8] = cv.v;
    }
    __syncthreads();
    // phase 2: transpose V out of LDS, write dim-major (swizzled)
    for (int it = threadIdx.x; it < 512; it += 256) {
        const int dd = it >> 3;
        const int k8 = it & 7;
        union { short s[8]; bf16x8 v; } o;
#pragma unroll
        for (int u = 0; u < 8; ++u)
            o.s[u] = vt[(k8 * 8 + u) * LDKP + dd];
        *(bf16x8*)&Vp[tile_s + dd * 64 + ((k8 ^ (dd & 7)) * 8)] = o.v;
    }
}

// One block = (group g, head hl, 128-query tile). 4 waves, 32 queries/wave.
// Double-buffered K/V DMA: stage(kt+1) issued after kf frag reads of tile kt;
// drained by the mid-loop P barrier + next top barrier (>= full compute phase
// of cover). ALL of R4's proven barrier orderings are preserved (the P
// round-trip barrier is back — R5's removal produced NaN).
__global__ __launch_bounds__(256, 3) void attn_kernel(
    const float* __restrict__ Q, float* __restrict__ O,
    const short* __restrict__ Kp, const short* __restrict__ Vp)
{
    __shared__ __align__(16) short ldsK[2][4096];    // 64 keys x 64 dims, swizzled
    __shared__ __align__(16) short ldsV[2][4096];    // 64 dims x 64 keys, swizzled
    __shared__ __align__(16) short ldsP[128 * LDKP]; // P round-trip

    const int bx = blockIdx.x;
    const int g  = bx / 320;
    const int r  = bx - g * 320;
    const int hl = r >> 6;
    const int qb = r & 63;
    const int h  = g * 5 + hl;
    const int qglob = qb * 128;
    const int seg   = qb >> (4 + g);
    const int tile0 = ((g == 0) ? 0 : (g == 1) ? 640 : 960) + (hl * (4 >> g) + seg) * 32;

    const int tid  = threadIdx.x;
    const int wave = tid >> 6;
    const int lane = tid & 63;
    const int ln   = lane & 15;
    const int quad = lane >> 4;

    auto stage = [&](int t, int buf) {
        const size_t tb = (size_t)(tile0 + t) << 13;   // 8 KB per tile
        const char* kgp = (const char*)Kp + tb + (wave << 11) + (lane << 4);
        const char* vgp = (const char*)Vp + tb + (wave << 11) + (lane << 4);
        char* klp = (char*)&ldsK[buf][0] + (wave << 11);
        char* vlp = (char*)&ldsV[buf][0] + (wave << 11);
        gld16(kgp,        klp);
        gld16(kgp + 1024, klp + 1024);
        gld16(vgp,        vlp);
        gld16(vgp + 1024, vlp + 1024);
    };

    stage(0, 0);   // prologue prefetch

    // head 15 belongs to no group: zero it here (d_out poisoned each run).
    if (g == 0 && hl == 0) {
        const float4 z = make_float4(0.f, 0.f, 0.f, 0.f);
        for (int i = tid; i < 2048; i += 256) {
            int row = qglob + (i >> 4);
            ((float4*)O)[(size_t)(row * 16 + 15) * 16 + (i & 15)] = z;
        }
    }

    // ---- Q fragments (B-operand of S^T = K.Q^T): lane holds Q[q=base+ln][dim=quad*8..+8]
    const float cs = 0.125f * 1.44269504088896f;   // scale * log2(e)
    bf16x8 qf[2][2];
#pragma unroll
    for (int m2 = 0; m2 < 2; ++m2) {
        int qrow = qglob + wave * 32 + m2 * 16 + ln;
        const float* qp = Q + ((size_t)(qrow * 16 + h)) * 64;
#pragma unroll
        for (int kh = 0; kh < 2; ++kh) {
            const float4* p4 = (const float4*)(qp + kh * 32 + quad * 8);
            float4 a = p4[0], b = p4[1];
            union { unsigned u[4]; bf16x8 v; } f;
            f.u[0] = pk2(a.x * cs, a.y * cs); f.u[1] = pk2(a.z * cs, a.w * cs);
            f.u[2] = pk2(b.x * cs, b.y * cs); f.u[3] = pk2(b.z * cs, b.w * cs);
            qf[m2][kh] = f.v;
        }
    }

    f32x4 oacc[2][4];
#pragma unroll
    for (int a = 0; a < 2; ++a)
#pragma unroll
        for (int b = 0; b < 4; ++b)
            oacc[a][b] = (f32x4){0.f, 0.f, 0.f, 0.f};
    float lp[2] = {0.f, 0.f};

    for (int kt = 0; kt < 32; ++kt) {
        const int cur = kt & 1;
        __syncthreads();   // drains DMA(kt); buf[cur] staged; buf[cur^1] reads (kt-1) done

        // ---- K A-fragments from current buffer (before next DMA issue)
        bf16x8 kf[4][2];
#pragma unroll
        for (int kg = 0; kg < 4; ++kg)
#pragma unroll
            for (int kh = 0; kh < 2; ++kh)
                kf[kg][kh] = *(const bf16x8*)&ldsK[cur][(kg * 16 + ln) * 64 + (((kh * 4 + quad) ^ (ln & 7)) * 8)];

        if (kt < 31) stage(kt + 1, cur ^ 1);   // prefetch next tile

        // ---- S^T = K.Q^T -> exp2 -> P (b64 writes, 4 consecutive keys/lane)
#pragma unroll
        for (int m2 = 0; m2 < 2; ++m2) {
            float lacc = 0.f;
#pragma unroll
            for (int kg = 0; kg < 4; ++kg) {
                f32x4 st = (f32x4){0.f, 0.f, 0.f, 0.f};
                st = __builtin_amdgcn_mfma_f32_16x16x32_bf16(kf[kg][0], qf[m2][0], st, 0, 0, 0);
                st = __builtin_amdgcn_mfma_f32_16x16x32_bf16(kf[kg][1], qf[m2][1], st, 0, 0, 0);
                float p0 = __builtin_amdgcn_exp2f(st[0]);
                float p1 = __builtin_amdgcn_exp2f(st[1]);
                float p2 = __builtin_amdgcn_exp2f(st[2]);
                float p3 = __builtin_amdgcn_exp2f(st[3]);
                lacc += (p0 + p1) + (p2 + p3);
                union { unsigned u[2]; s16x4 s; } pc;
                pc.u[0] = pk2(p0, p1); pc.u[1] = pk2(p2, p3);
                *(s16x4*)&ldsP[(wave * 32 + m2 * 16 + ln) * LDKP + kg * 16 + quad * 4] = pc.s;
            }
            lp[m2] += lacc;
        }
        __syncthreads();   // P visible before A-frag reads (R4-proven ordering)

        // ---- P.V  (B-frags: lane holds V[key=kh*32+quad*8..+8][dim=n4*16+ln])
        bf16x8 vf[4][2];
#pragma unroll
        for (int n4 = 0; n4 < 4; ++n4)
#pragma unroll
            for (int kh = 0; kh < 2; ++kh)
                vf[n4][kh] = *(const bf16x8*)&ldsV[cur][(n4 * 16 + ln) * 64 + (((kh * 4 + quad) ^ (ln & 7)) * 8)];
#pragma unroll
        for (int m2 = 0; m2 < 2; ++m2) {
            const short* prow = &ldsP[(wave * 32 + m2 * 16 + ln) * LDKP];
            bf16x8 ap0 = *(const bf16x8*)(prow + quad * 8);
            bf16x8 ap1 = *(const bf16x8*)(prow + 32 + quad * 8);
#pragma unroll
            for (int n4 = 0; n4 < 4; ++n4) {
                oacc[m2][n4] = __builtin_amdgcn_mfma_f32_16x16x32_bf16(ap0, vf[n4][0], oacc[m2][n4], 0, 0, 0);
                oacc[m2][n4] = __builtin_amdgcn_mfma_f32_16x16x32_bf16(ap1, vf[n4][1], oacc[m2][n4], 0, 0, 0);
            }
        }
    }

    // ---- deferred l reduction across the 4 quads
    lp[0] += __shfl_xor(lp[0], 16, 64);
    lp[0] += __shfl_xor(lp[0], 32, 64);
    lp[1] += __shfl_xor(lp[1], 16, 64);
    lp[1] += __shfl_xor(lp[1], 32, 64);

    // ---- epilogue: O / l (C-layout: row=quad*4+rg, col=n4*16+ln)
#pragma unroll
    for (int m2 = 0; m2 < 2; ++m2) {
#pragma unroll
        for (int rg = 0; rg < 4; ++rg) {
            float lv  = __shfl(lp[m2], quad * 4 + rg, 64);
            float inv = 1.0f / lv;
            int qrow = qglob + wave * 32 + m2 * 16 + quad * 4 + rg;
            float* op = O + ((size_t)(qrow * 16 + h)) * 64;
#pragma unroll
            for (int n4 = 0; n4 < 4; ++n4)
                op[n4 * 16 + ln] = oacc[m2][n4][rg] * inv;
        }
    }
}

extern "C" void kernel_launch(void* const* d_in, const int* in_sizes, int n_in,
                              void* d_out, int out_size, void* d_ws, size_t ws_size,
                              hipStream_t stream) {
    const float* q = (const float*)d_in[0];
    const float* k = (const float*)d_in[1];
    const float* v = (const float*)d_in[2];
    float* out = (float*)d_out;
    short* Kp = (short*)d_ws;                       // 1120 tiles * 8 KB = 9.18 MB
    short* Vp = Kp + (size_t)1120 * 4096;           // + 9.18 MB

    gather_kv<<<1120, 256, 0, stream>>>(k, v, Kp, Vp);
    attn_kernel<<<960, 256, 0, stream>>>(q, out, Kp, Vp);
}